// Round 3
// baseline (386.229 us; speedup 1.0000x reference)
//
#include <hip/hip_runtime.h>
#include <stdint.h>

typedef __attribute__((ext_vector_type(8))) short short8;
typedef __attribute__((ext_vector_type(4))) short s16x4;
typedef __attribute__((ext_vector_type(4))) float f32x4;
typedef __attribute__((ext_vector_type(4))) uint32_t u32x4;
typedef __attribute__((ext_vector_type(2))) uint32_t u32x2;

#define LOG2E   1.4426950408889634f
#define SCALE_Q 0.17677669529663687f

__device__ __forceinline__ uint16_t f2bf(float f) {
    uint32_t u = __builtin_bit_cast(uint32_t, f);
    u += 0x7FFFu + ((u >> 16) & 1u);
    return (uint16_t)(u >> 16);
}

// packed f32x2 -> bf16x2 (RNE), single VALU op
__device__ __forceinline__ uint32_t cvtpk(float a, float b) {
    uint32_t r;
    asm("v_cvt_pk_bf16_f32 %0, %1, %2" : "=v"(r) : "v"(a), "v"(b));
    return r;
}

// ws layout (bytes):
//   0      : wq  bf16 [384][128]   qkv weights; q-rows pre-scaled by SCALE*LOG2E
//   98304  : bq  f32  [384]        qkv bias; q-part pre-scaled by SCALE*LOG2E
//   99840  : wp  bf16 [128][128]   proj weights
//   132608 : bTs f32  [4][64][64]  rel-pos bias gathered per head, scaled by LOG2E
__global__ void prep_kernel(const float* __restrict__ qkv_w, const float* __restrict__ qkv_b,
                            const float* __restrict__ proj_w, const float* __restrict__ rel_b,
                            uint16_t* __restrict__ wq, float* __restrict__ bq,
                            uint16_t* __restrict__ wp, float* __restrict__ bTs) {
    int t = blockIdx.x * 256 + threadIdx.x;
    if (t < 384 * 128) {
        int o = t >> 7;
        float s = (o < 128) ? SCALE_Q * LOG2E : 1.0f;
        wq[t] = f2bf(qkv_w[t] * s);
    }
    if (t < 384) bq[t] = qkv_b[t] * ((t < 128) ? SCALE_Q * LOG2E : 1.0f);
    if (t < 128 * 128) wp[t] = f2bf(proj_w[t]);
    if (t < 4 * 64 * 64) {
        int h = t & 3, nm = t >> 2, n = nm >> 6, m = nm & 63;
        int idx = ((n >> 3) - (m >> 3) + 7) * 15 + ((n & 7) - (m & 7) + 7);
        bTs[(h * 64 + n) * 64 + m] = rel_b[idx * 4 + h] * LOG2E;
    }
}

// One block per window; 4 waves = 4 heads.
// LDS: S1 = QKVs[64][264] (Q,K) -> later O[64][136];  Vt = V^T[128][72].
__global__ __launch_bounds__(256, 3) void winattn_kernel(
    const float* __restrict__ x, const float* __restrict__ mask,
    const uint16_t* __restrict__ wq, const float* __restrict__ bq,
    const uint16_t* __restrict__ wp, const float* __restrict__ pb,
    const float* __restrict__ bTs, float* __restrict__ out)
{
    __shared__ uint16_t S1[16896];   // 33 KB
    __shared__ uint16_t Vt[9216];    // 18 KB

    const int b    = blockIdx.x;
    const int w    = b & 63;
    const int wid  = threadIdx.x >> 6;
    const int lane = threadIdx.x & 63;
    const int l15  = lane & 15;
    const int lg   = lane >> 4;

    // ---------- Phase 1: QKV^T = Wqkv * x^T  (A=W rows o, B=x^T cols token) ----------
    short8 xa[4][4];   // x fragments, shared across all 6 o-tiles of this wave
    const float* xb = x + (size_t)b * 8192;
    #pragma unroll
    for (int tt = 0; tt < 4; ++tt) {
      #pragma unroll
      for (int ks = 0; ks < 4; ++ks) {
        const float* p = xb + (tt*16 + l15)*128 + ks*32 + lg*8;
        f32x4 f0 = *(const f32x4*)p;
        f32x4 f1 = *(const f32x4*)(p + 4);
        u32x4 u = { cvtpk(f0[0],f0[1]), cvtpk(f0[2],f0[3]),
                    cvtpk(f1[0],f1[1]), cvtpk(f1[2],f1[3]) };
        xa[tt][ks] = __builtin_bit_cast(short8, u);
      }
    }
    #pragma unroll
    for (int ct = 0; ct < 6; ++ct) {
        const int tile = wid + 4*ct;     // o-tiles strided: Q=ct{0,1}, K=ct{2,3}, V=ct{4,5}
        short8 wb[4];
        #pragma unroll
        for (int ks = 0; ks < 4; ++ks)
            wb[ks] = *(const short8*)(wq + (tile*16 + l15)*128 + ks*32 + lg*8);
        f32x4 bqv = *(const f32x4*)(bq + tile*16 + lg*4);
        #pragma unroll
        for (int tt = 0; tt < 4; ++tt) {
            f32x4 acc = {0.f,0.f,0.f,0.f};
            #pragma unroll
            for (int ks = 0; ks < 4; ++ks)
                acc = __builtin_amdgcn_mfma_f32_16x16x32_bf16(wb[ks], xa[tt][ks], acc, 0,0,0);
            const int token = tt*16 + l15;
            if (ct < 4) {
                // Q/K: QKVs[token][o], 4 consecutive o packed -> ds_write_b64
                u32x2 wv = { cvtpk(acc[0]+bqv[0], acc[1]+bqv[1]),
                             cvtpk(acc[2]+bqv[2], acc[3]+bqv[3]) };
                *(u32x2*)&S1[token*264 + tile*16 + lg*4] = wv;
            } else {
                // V^T[vd][token]
                const int vd0 = tile*16 + lg*4 - 256;
                #pragma unroll
                for (int r = 0; r < 4; ++r)
                    Vt[(vd0 + r)*72 + token] = (uint16_t)cvtpk(acc[r]+bqv[r], acc[r]+bqv[r]);
            }
        }
    }
    __syncthreads();   // barrier A: QKV staged

    // ---------- Phase 2: S^T = K * Q^T  (softmax axis m becomes lane-local) ----------
    const int h = wid;
    short8 kf[4], qf[4];
    #pragma unroll
    for (int mt = 0; mt < 4; ++mt)
        kf[mt] = *(const short8*)&S1[(mt*16 + l15)*264 + 128 + h*32 + lg*8];
    #pragma unroll
    for (int nt = 0; nt < 4; ++nt)
        qf[nt] = *(const short8*)&S1[(nt*16 + l15)*264 + h*32 + lg*8];
    __syncthreads();   // barrier B: all QKVs reads in regs; S1 free for O

    f32x4 sacc[4][4];  // [mt][nt]: S^T[m = mt*16+lg*4+r][n = nt*16+l15]
    #pragma unroll
    for (int mt = 0; mt < 4; ++mt) {
      #pragma unroll
      for (int nt = 0; nt < 4; ++nt) {
        f32x4 z = {0.f,0.f,0.f,0.f};
        sacc[mt][nt] = __builtin_amdgcn_mfma_f32_16x16x32_bf16(kf[mt], qf[nt], z, 0,0,0);
      }
    }

    const float* bTh = bTs + h*4096;
    const float* mkw = mask + w*4096;
    float rcpv[4];
    #pragma unroll
    for (int nt = 0; nt < 4; ++nt) {
        const int off = (nt*16 + l15)*64 + lg*4;
        float mx = -3.0e38f;
        #pragma unroll
        for (int mt = 0; mt < 4; ++mt) {
            f32x4 bb = *(const f32x4*)(bTh + off + mt*16);
            f32x4 mm = *(const f32x4*)(mkw + off + mt*16);
            #pragma unroll
            for (int r = 0; r < 4; ++r) {
                float t = fmaf(mm[r], LOG2E, sacc[mt][nt][r] + bb[r]);
                sacc[mt][nt][r] = t;
                mx = fmaxf(mx, t);
            }
        }
        mx = fmaxf(mx, __shfl_xor(mx, 16));
        mx = fmaxf(mx, __shfl_xor(mx, 32));
        float sum = 0.f;
        #pragma unroll
        for (int mt = 0; mt < 4; ++mt) {
          #pragma unroll
          for (int r = 0; r < 4; ++r) {
            float p = exp2f(sacc[mt][nt][r] - mx);
            sacc[mt][nt][r] = p;
            sum += p;
          }
        }
        sum += __shfl_xor(sum, 16);
        sum += __shfl_xor(sum, 32);
        rcpv[nt] = __builtin_amdgcn_rcpf(sum);   // deferred into O epilogue (n lane-local)
    }

    // P fragments fully in-register (k-perm: m = 32a + 16*(e>>2) + 4*lg + (e&3))
    short8 pa[4][2];
    #pragma unroll
    for (int nt = 0; nt < 4; ++nt) {
      #pragma unroll
      for (int a = 0; a < 2; ++a) {
        u32x4 u = { cvtpk(sacc[2*a][nt][0],   sacc[2*a][nt][1]),
                    cvtpk(sacc[2*a][nt][2],   sacc[2*a][nt][3]),
                    cvtpk(sacc[2*a+1][nt][0], sacc[2*a+1][nt][1]),
                    cvtpk(sacc[2*a+1][nt][2], sacc[2*a+1][nt][3]) };
        pa[nt][a] = __builtin_bit_cast(short8, u);
      }
    }

    // ---------- Phase 3: O^T = V^T * P^T  (V^T b64-pairs match the same k-perm) ----------
    f32x4 oacc[2][4];  // [dt][nt]
    #pragma unroll
    for (int dt = 0; dt < 2; ++dt) {
        const uint16_t* vrow = Vt + (h*32 + dt*16 + l15)*72;
        short8 va[2];
        #pragma unroll
        for (int a = 0; a < 2; ++a) {
            s16x4 x0 = *(const s16x4*)(vrow + a*32 + lg*4);
            s16x4 x1 = *(const s16x4*)(vrow + a*32 + 16 + lg*4);
            va[a] = __builtin_shufflevector(x0, x1, 0,1,2,3,4,5,6,7);
        }
        #pragma unroll
        for (int nt = 0; nt < 4; ++nt) {
            f32x4 acc = {0.f,0.f,0.f,0.f};
            acc = __builtin_amdgcn_mfma_f32_16x16x32_bf16(va[0], pa[nt][0], acc, 0,0,0);
            acc = __builtin_amdgcn_mfma_f32_16x16x32_bf16(va[1], pa[nt][1], acc, 0,0,0);
            oacc[dt][nt] = acc;
        }
    }

    // O[n][d] packed b64 stores (aliases QKVs region; safe after barrier B)
    #pragma unroll
    for (int dt = 0; dt < 2; ++dt) {
      #pragma unroll
      for (int nt = 0; nt < 4; ++nt) {
        const float rc = rcpv[nt];
        f32x4 o = oacc[dt][nt];
        u32x2 wv = { cvtpk(o[0]*rc, o[1]*rc), cvtpk(o[2]*rc, o[3]*rc) };
        *(u32x2*)&S1[(nt*16 + l15)*136 + h*32 + dt*16 + lg*4] = wv;
      }
    }
    __syncthreads();   // barrier C: O staged

    // ---------- Phase 4: out = O * Wp^T + pb ----------
    short8 of[4][4];
    #pragma unroll
    for (int rt = 0; rt < 4; ++rt)
      #pragma unroll
      for (int ks = 0; ks < 4; ++ks)
        of[rt][ks] = *(const short8*)&S1[(rt*16 + l15)*136 + ks*32 + lg*8];

    float* outb = out + (size_t)b * 8192;
    #pragma unroll
    for (int ct = 0; ct < 2; ++ct) {
        const int cbase = wid*32 + ct*16;
        short8 wf[4];
        #pragma unroll
        for (int ks = 0; ks < 4; ++ks)
            wf[ks] = *(const short8*)(wp + (cbase + l15)*128 + ks*32 + lg*8);
        const float pbias = pb[cbase + l15];
        #pragma unroll
        for (int rt = 0; rt < 4; ++rt) {
            f32x4 acc = {0.f,0.f,0.f,0.f};
            #pragma unroll
            for (int ks = 0; ks < 4; ++ks)
                acc = __builtin_amdgcn_mfma_f32_16x16x32_bf16(of[rt][ks], wf[ks], acc, 0,0,0);
            #pragma unroll
            for (int r = 0; r < 4; ++r)
                outb[(rt*16 + lg*4 + r)*128 + cbase + l15] = acc[r] + pbias;
        }
    }
}

extern "C" void kernel_launch(void* const* d_in, const int* in_sizes, int n_in,
                              void* d_out, int out_size, void* d_ws, size_t ws_size,
                              hipStream_t stream) {
    const float* x      = (const float*)d_in[0];
    const float* mask   = (const float*)d_in[1];
    const float* qkv_w  = (const float*)d_in[2];
    const float* qkv_b  = (const float*)d_in[3];
    const float* proj_w = (const float*)d_in[4];
    const float* proj_b = (const float*)d_in[5];
    const float* rel_b  = (const float*)d_in[6];
    float* out = (float*)d_out;

    char* ws = (char*)d_ws;
    uint16_t* wq  = (uint16_t*)ws;
    float*    bq  = (float*)(ws + 98304);
    uint16_t* wp  = (uint16_t*)(ws + 99840);
    float*    bTs = (float*)(ws + 132608);

    const int B_ = in_sizes[0] / (64 * 128);   // 8192

    hipLaunchKernelGGL(prep_kernel, dim3(192), dim3(256), 0, stream,
                       qkv_w, qkv_b, proj_w, rel_b, wq, bq, wp, bTs);
    hipLaunchKernelGGL(winattn_kernel, dim3(B_), dim3(256), 0, stream,
                       x, mask, wq, bq, wp, proj_b, bTs, out);
}